// Round 10
// baseline (195.273 us; speedup 1.0000x reference)
//
#include <hip/hip_runtime.h>
#include <hip/hip_bf16.h>

#define BB 4
#define TT 4096
#define HH 2048
#define NSLOT 64
#define KD 256
#define VD 256
#define BT (BB*TT)
#define NEGV (-1e9f)
#define EPSV 1e-5f

typedef __attribute__((ext_vector_type(8))) short short8;
typedef __attribute__((ext_vector_type(4))) float floatx4;

union B8 { short8 v; unsigned short u[8]; };

__device__ inline unsigned short f2bf(float x) {
  unsigned u = __float_as_uint(x);
  return (unsigned short)((u + 0x7FFFu + ((u >> 16) & 1u)) >> 16);
}
__device__ inline float bf2f(unsigned short h) {
  return __uint_as_float(((unsigned)h) << 16);
}
__device__ inline void cvt8(const float4 a, const float4 b, B8& h, B8& l) {
  const float f[8] = {a.x, a.y, a.z, a.w, b.x, b.y, b.z, b.w};
#pragma unroll
  for (int j = 0; j < 8; ++j) {
    unsigned short hh = f2bf(f[j]);
    h.u[j] = hh;
    l.u[j] = f2bf(f[j] - bf2f(hh));
  }
}

// ---------------- mask dtype detection + conversion (16 blocks) -------------
__global__ void mask_convert_kernel(const void* valid_raw, const void* hist_raw,
                                    int* valid_int, int* hist_int) {
  __shared__ int mode_s;
  const int tid = threadIdx.x;
  if (tid == 0) {
    const unsigned int* w = (const unsigned int*)valid_raw;
    int all01 = 1, anyfloat = 0;
    for (int i = 0; i < 64; ++i) {
      unsigned int x = w[i];
      if (x != 0u && x != 1u) all01 = 0;
      if (x == 0x3F800000u) anyfloat = 1;
    }
    mode_s = all01 ? 0 : (anyfloat ? 1 : 2);
  }
  __syncthreads();
  const int mode = mode_s;
  if (blockIdx.x == 0) {
    const int* vi = (const int*)valid_raw;
    const float* vf = (const float*)valid_raw;
    const unsigned char* vb = (const unsigned char*)valid_raw;
    for (int i = tid; i < BB * NSLOT; i += blockDim.x)
      valid_int[i] = (mode == 0) ? (vi[i] != 0)
                   : (mode == 1) ? (vf[i] != 0.0f)
                                 : (vb[i] != 0);
  }
  {
    const int* vi = (const int*)hist_raw;
    const float* vf = (const float*)hist_raw;
    const unsigned char* vb = (const unsigned char*)hist_raw;
    const int base = blockIdx.x * 1024;
    for (int i = tid; i < 1024; i += blockDim.x) {
      const int g = base + i;
      hist_int[g] = (mode == 0) ? (vi[g] != 0)
                  : (mode == 1) ? (vf[g] != 0.0f)
                                : (vb[g] != 0);
    }
  }
}

// ---------------- PK[b,n,h] = sum_k keys[b,n,k] * Wq[k,h]  (fp32) -----------
__global__ __launch_bounds__(256) void pk_kernel(const float* __restrict__ keys,
                                                 const float* __restrict__ Wq,
                                                 float* __restrict__ PK) {
  const int b = blockIdx.x >> 5;
  const int h0 = (blockIdx.x & 31) * 64;
  __shared__ float ks[64][260];
  const int tid = threadIdx.x;
  const float* kb = keys + (size_t)b * 64 * 256;
  for (int i = tid; i < 64 * 64; i += 256) {
    const int n = i >> 6, k4 = (i & 63) * 4;
    *(float4*)&ks[n][k4] = *(const float4*)&kb[n * 256 + k4];
  }
  __syncthreads();
  const int h = h0 + (tid & 63);
  const int ng = tid >> 6;
  float acc[16] = {};
  for (int k = 0; k < 256; ++k) {
    const float wq = Wq[(size_t)k * HH + h];
#pragma unroll
    for (int i = 0; i < 16; ++i) acc[i] += ks[i * 4 + ng][k] * wq;
  }
#pragma unroll
  for (int i = 0; i < 16; ++i)
    PK[((size_t)b * 64 + i * 4 + ng) * HH + h] = acc[i];
}

// -------- PK -> hi/lo bf16 MFMA-fragment layout (grid 256) ------------------
__global__ __launch_bounds__(64) void pkfrag_kernel(const float* __restrict__ PK,
                                                    unsigned short* __restrict__ PKh,
                                                    unsigned short* __restrict__ PKl) {
  const int b = blockIdx.x >> 6, kc = blockIdx.x & 63;
  const int lane = threadIdx.x, fr = lane & 15, hi4 = lane >> 4;
#pragma unroll
  for (int nt = 0; nt < 4; ++nt) {
    const float* src = &PK[((size_t)b * 64 + nt * 16 + fr) * HH + kc * 32 + hi4 * 8];
    const float4 a = *(const float4*)src;
    const float4 c = *(const float4*)(src + 4);
    B8 h, l;
    cvt8(a, c, h, l);
    const size_t off = (((size_t)(b * 64 + kc) * 4 + nt) * 64 + lane) * 8;
    *(short8*)&PKh[off] = h.v;
    *(short8*)&PKl[off] = l.v;
  }
}

// -------- VW[b][n][h] = sum_v vals[b,n,v] * Wo[h,v] -> bf16 [b][64][2048] ---
// grid 128: b = blk>>5, h0 = (blk&31)*64. Both operands staged in LDS.
__global__ __launch_bounds__(256) void vw_kernel(const float* __restrict__ vals,
                                                 const float* __restrict__ Wo,
                                                 unsigned short* __restrict__ VWb) {
  const int b = blockIdx.x >> 5;
  const int h0 = (blockIdx.x & 31) * 64;
  __shared__ float vals_s[64][260];
  __shared__ float wo_s[64][261];   // 261 % 32 = 5, gcd(5,32)=1 -> conflict-free
  const int tid = threadIdx.x;
  const float* vb = vals + (size_t)b * 64 * 256;
  for (int i = tid; i < 64 * 64; i += 256) {
    const int r = i >> 6, c4 = (i & 63) * 4;
    *(float4*)&vals_s[r][c4] = *(const float4*)&vb[r * 256 + c4];
    *(float4*)&wo_s[r][c4] = *(const float4*)&Wo[(size_t)(h0 + r) * 256 + c4];
  }
  __syncthreads();
  const int hloc = tid & 63;
  const int ng = tid >> 6;
  float acc[16] = {};
  for (int v = 0; v < 256; ++v) {
    const float wo = wo_s[hloc][v];
#pragma unroll
    for (int i = 0; i < 16; ++i) acc[i] += vals_s[i * 4 + ng][v] * wo;
  }
#pragma unroll
  for (int i = 0; i < 16; ++i)
    VWb[((size_t)b * 64 + i * 4 + ng) * HH + h0 + hloc] = f2bf(acc[i]);
}

// -------- attn v10: scores (split-bf16 MFMA) + softmax -> P bf16 ------------
// 16 tok/block, double-buffered LDS A, PK reg prefetch; grid 1024
__global__ __launch_bounds__(256, 4) void attn_kernel(
    const float* __restrict__ hs,
    const unsigned short* __restrict__ PKh,
    const unsigned short* __restrict__ PKl,
    const int* __restrict__ valid,
    const int* __restrict__ hist,
    unsigned short* __restrict__ PB) {   // [BT][64] bf16
  const int t0 = blockIdx.x * 16;
  const int b = blockIdx.x >> 8;         // 256 blocks per batch
  const int tid = threadIdx.x;
  const int w = tid >> 6, lane = tid & 63;
  const int fr = lane & 15, hi4 = lane >> 4;

  __shared__ __align__(16) unsigned short Ah[2][16][136], Al[2][16][136];
  __shared__ float S[16][68];

  floatx4 accA = (floatx4){0.f, 0.f, 0.f, 0.f};
  floatx4 accB = accA, accC = accA;

  const int sr = tid >> 4;        // token row 0..15
  const int sg = tid & 15;        // 8-float col group
  const float* gbase = &hs[(size_t)(t0 + sr) * HH + sg * 8];

  float4 va0 = *(const float4*)gbase;
  float4 va1 = *(const float4*)(gbase + 4);
  {
    B8 h_, l_;
    cvt8(va0, va1, h_, l_);
    *(short8*)&Ah[0][sr][sg * 8] = h_.v;
    *(short8*)&Al[0][sr][sg * 8] = l_.v;
  }
  va0 = *(const float4*)(gbase + 128);
  va1 = *(const float4*)(gbase + 132);
  short8 bhc[4], blc[4];
#pragma unroll
  for (int kcL = 0; kcL < 4; ++kcL) {
    const size_t off = ((size_t)(b * 64 + kcL) * 4 + w) * 512 + lane * 8;
    bhc[kcL] = *(const short8*)&PKh[off];
    blc[kcL] = *(const short8*)&PKl[off];
  }
  __syncthreads();

  for (int s = 0; s < 16; ++s) {
    const int buf = s & 1;
    if (s < 15) {
      B8 h_, l_;
      cvt8(va0, va1, h_, l_);
      *(short8*)&Ah[buf ^ 1][sr][sg * 8] = h_.v;
      *(short8*)&Al[buf ^ 1][sr][sg * 8] = l_.v;
    }
    if (s < 14) {
      va0 = *(const float4*)(gbase + (s + 2) * 128);
      va1 = *(const float4*)(gbase + (s + 2) * 128 + 4);
    }
    short8 bhn[4], bln[4];
    if (s < 15) {
#pragma unroll
      for (int kcL = 0; kcL < 4; ++kcL) {
        const size_t off = ((size_t)(b * 64 + (s + 1) * 4 + kcL) * 4 + w) * 512 + lane * 8;
        bhn[kcL] = *(const short8*)&PKh[off];
        bln[kcL] = *(const short8*)&PKl[off];
      }
    }
#pragma unroll
    for (int kcL = 0; kcL < 4; ++kcL) {
      const short8 ah = *(const short8*)&Ah[buf][fr][kcL * 32 + hi4 * 8];
      const short8 al = *(const short8*)&Al[buf][fr][kcL * 32 + hi4 * 8];
      accA = __builtin_amdgcn_mfma_f32_16x16x32_bf16(ah, bhc[kcL], accA, 0, 0, 0);
      accB = __builtin_amdgcn_mfma_f32_16x16x32_bf16(al, bhc[kcL], accB, 0, 0, 0);
      accC = __builtin_amdgcn_mfma_f32_16x16x32_bf16(ah, blc[kcL], accC, 0, 0, 0);
    }
    __syncthreads();
    if (s < 15) {
#pragma unroll
      for (int kcL = 0; kcL < 4; ++kcL) { bhc[kcL] = bhn[kcL]; blc[kcL] = bln[kcL]; }
    }
  }

  const floatx4 acc = accA + accB + accC;
#pragma unroll
  for (int rr = 0; rr < 4; ++rr)
    S[hi4 * 4 + rr][w * 16 + fr] = acc[rr];
  __syncthreads();

  // softmax + masks -> P (wave w handles tokens w*4..w*4+3; lane = slot)
  const int vmy = valid[b * 64 + lane];
  const unsigned long long bal = __ballot(vmy != 0);
  const float any = (bal != 0ull) ? 1.0f : 0.0f;
#pragma unroll
  for (int i = 0; i < 4; ++i) {
    const int tt = w * 4 + i;
    const int tok = t0 + tt;
    float s = vmy ? S[tt][lane] : NEGV;
    float m = s;
#pragma unroll
    for (int o = 32; o; o >>= 1) m = fmaxf(m, __shfl_xor(m, o));
    const float e = __expf(s - m);
    float sum = e;
#pragma unroll
    for (int o = 32; o; o >>= 1) sum += __shfl_xor(sum, o);
    const float allowed = hist[tok] ? 0.0f : 1.0f;
    PB[(size_t)tok * 64 + lane] = f2bf(e / sum * any * allowed);
  }
}

// -------- fused output: out = LN(hs + P·VW^T) -------------------------------
// 8 tokens/block, 256 thr (4 waves). K=64 VALU contraction, acc[64] fp32,
// LN stats via shfl + LDS. grid 2048.
__global__ __launch_bounds__(256, 4) void fuse_out_kernel(
    const unsigned short* __restrict__ PB,   // [BT][64] bf16
    const unsigned short* __restrict__ VWb,  // [B][64][2048] bf16
    const float* __restrict__ RES,           // hs
    const float* __restrict__ gamma,
    const float* __restrict__ beta,
    float* __restrict__ out) {
  const int tok0 = blockIdx.x * 8;
  const int b = tok0 >> 12;
  const int tid = threadIdx.x;
  const int w = tid >> 6;
  const int col0 = tid * 8;

  __shared__ float PlT[64][8];      // n-major: PlT[n][tok]
  __shared__ float part[8][4][2];
  __shared__ float stats[8][2];

  {
    const int e0 = tid, e1 = tid + 256;
    PlT[e0 & 63][e0 >> 6] = bf2f(PB[(size_t)tok0 * 64 + e0]);
    PlT[e1 & 63][e1 >> 6] = bf2f(PB[(size_t)tok0 * 64 + e1]);
  }
  __syncthreads();

  float acc[64];
#pragma unroll
  for (int i = 0; i < 64; ++i) acc[i] = 0.f;

  const unsigned short* vwrow = &VWb[(size_t)b * 64 * HH + col0];
#pragma unroll 2
  for (int n = 0; n < 64; ++n) {
    B8 t;
    t.v = *(const short8*)&vwrow[(size_t)n * HH];
    float wv[8];
#pragma unroll
    for (int j = 0; j < 8; ++j) wv[j] = bf2f(t.u[j]);
    float pv[8];
    *(float4*)&pv[0] = *(const float4*)&PlT[n][0];   // broadcast reads
    *(float4*)&pv[4] = *(const float4*)&PlT[n][4];
#pragma unroll
    for (int tk = 0; tk < 8; ++tk)
#pragma unroll
      for (int c = 0; c < 8; ++c)
        acc[tk * 8 + c] = fmaf(pv[tk], wv[c], acc[tk * 8 + c]);
  }

  // residual add + per-token stats
#pragma unroll
  for (int tk = 0; tk < 8; ++tk) {
    const float* rr = &RES[(size_t)(tok0 + tk) * HH + col0];
    const float4 r0 = *(const float4*)rr;
    const float4 r1 = *(const float4*)(rr + 4);
    float rv[8];
    *(float4*)&rv[0] = r0;
    *(float4*)&rv[4] = r1;
    float s = 0.f, q = 0.f;
#pragma unroll
    for (int c = 0; c < 8; ++c) {
      const float x = acc[tk * 8 + c] + rv[c];
      acc[tk * 8 + c] = x;
      s += x;
      q += x * x;
    }
#pragma unroll
    for (int o = 32; o; o >>= 1) {
      s += __shfl_xor(s, o);
      q += __shfl_xor(q, o);
    }
    if ((tid & 63) == 0) {
      part[tk][w][0] = s;
      part[tk][w][1] = q;
    }
  }
  __syncthreads();
  if (tid < 8) {
    float S = 0.f, Q = 0.f;
#pragma unroll
    for (int ww = 0; ww < 4; ++ww) {
      S += part[tid][ww][0];
      Q += part[tid][ww][1];
    }
    const float mu = S * (1.0f / HH);
    const float var = Q * (1.0f / HH) - mu * mu;
    stats[tid][0] = mu;
    stats[tid][1] = rsqrtf(var + EPSV);
  }
  __syncthreads();

  float gv[8], bv[8];
  *(float4*)&gv[0] = *(const float4*)&gamma[col0];
  *(float4*)&gv[4] = *(const float4*)&gamma[col0 + 4];
  *(float4*)&bv[0] = *(const float4*)&beta[col0];
  *(float4*)&bv[4] = *(const float4*)&beta[col0 + 4];

#pragma unroll
  for (int tk = 0; tk < 8; ++tk) {
    const float mu = stats[tk][0], inv = stats[tk][1];
    float4 o0, o1;
    o0.x = (acc[tk * 8 + 0] - mu) * inv * gv[0] + bv[0];
    o0.y = (acc[tk * 8 + 1] - mu) * inv * gv[1] + bv[1];
    o0.z = (acc[tk * 8 + 2] - mu) * inv * gv[2] + bv[2];
    o0.w = (acc[tk * 8 + 3] - mu) * inv * gv[3] + bv[3];
    o1.x = (acc[tk * 8 + 4] - mu) * inv * gv[4] + bv[4];
    o1.y = (acc[tk * 8 + 5] - mu) * inv * gv[5] + bv[5];
    o1.z = (acc[tk * 8 + 6] - mu) * inv * gv[6] + bv[6];
    o1.w = (acc[tk * 8 + 7] - mu) * inv * gv[7] + bv[7];
    float* orow = &out[(size_t)(tok0 + tk) * HH + col0];
    *(float4*)orow = o0;
    *(float4*)(orow + 4) = o1;
  }
}

extern "C" void kernel_launch(void* const* d_in, const int* in_sizes, int n_in,
                              void* d_out, int out_size, void* d_ws, size_t ws_size,
                              hipStream_t stream) {
  const float* hs    = (const float*)d_in[0];
  const float* keys  = (const float*)d_in[1];
  const float* vals  = (const float*)d_in[2];
  const float* Wq    = (const float*)d_in[3];
  const float* Wo    = (const float*)d_in[4];
  const float* gamma = (const float*)d_in[5];
  const float* beta  = (const float*)d_in[6];
  const void* valid_raw = d_in[7];
  const void* hist_raw  = d_in[8];
  float* out = (float*)d_out;

  char* w = (char*)d_ws;
  float* PK            = (float*)w;                           // 2 MB
  unsigned short* PKh  = (unsigned short*)(w + (2u << 20));   // 1 MB
  unsigned short* PKl  = (unsigned short*)(w + (3u << 20));   // 1 MB
  unsigned short* VWb  = (unsigned short*)(w + (4u << 20));   // 1 MB
  unsigned short* PB   = (unsigned short*)(w + (5u << 20));   // 2 MB
  int* valid_int = (int*)(w + (7u << 20));
  int* hist_int  = valid_int + BB * NSLOT;

  mask_convert_kernel<<<dim3(16), dim3(256), 0, stream>>>(valid_raw, hist_raw,
                                                          valid_int, hist_int);
  pk_kernel<<<dim3(128), dim3(256), 0, stream>>>(keys, Wq, PK);
  pkfrag_kernel<<<dim3(256), dim3(64), 0, stream>>>(PK, PKh, PKl);
  vw_kernel<<<dim3(128), dim3(256), 0, stream>>>(vals, Wo, VWb);
  attn_kernel<<<dim3(BT / 16), dim3(256), 0, stream>>>(
      hs, PKh, PKl, valid_int, hist_int, PB);
  fuse_out_kernel<<<dim3(BT / 8), dim3(256), 0, stream>>>(
      PB, VWb, hs, gamma, beta, out);
}

// Round 11
// 172.265 us; speedup vs baseline: 1.1336x; 1.1336x over previous
//
#include <hip/hip_runtime.h>
#include <hip/hip_bf16.h>

#define BB 4
#define TT 4096
#define HH 2048
#define NSLOT 64
#define KD 256
#define VD 256
#define BT (BB*TT)
#define NEGV (-1e9f)
#define EPSV 1e-5f

typedef __attribute__((ext_vector_type(8))) short short8;
typedef __attribute__((ext_vector_type(4))) float floatx4;

union B8 { short8 v; unsigned short u[8]; };

__device__ inline unsigned short f2bf(float x) {
  unsigned u = __float_as_uint(x);
  return (unsigned short)((u + 0x7FFFu + ((u >> 16) & 1u)) >> 16);
}
__device__ inline float bf2f(unsigned short h) {
  return __uint_as_float(((unsigned)h) << 16);
}
__device__ inline void cvt8(const float4 a, const float4 b, B8& h, B8& l) {
  const float f[8] = {a.x, a.y, a.z, a.w, b.x, b.y, b.z, b.w};
#pragma unroll
  for (int j = 0; j < 8; ++j) {
    unsigned short hh = f2bf(f[j]);
    h.u[j] = hh;
    l.u[j] = f2bf(f[j] - bf2f(hh));
  }
}

// ---------------- mask dtype detection + conversion (16 blocks) -------------
__global__ void mask_convert_kernel(const void* valid_raw, const void* hist_raw,
                                    int* valid_int, int* hist_int) {
  __shared__ int mode_s;
  const int tid = threadIdx.x;
  if (tid == 0) {
    const unsigned int* w = (const unsigned int*)valid_raw;
    int all01 = 1, anyfloat = 0;
    for (int i = 0; i < 64; ++i) {
      unsigned int x = w[i];
      if (x != 0u && x != 1u) all01 = 0;
      if (x == 0x3F800000u) anyfloat = 1;
    }
    mode_s = all01 ? 0 : (anyfloat ? 1 : 2);
  }
  __syncthreads();
  const int mode = mode_s;
  if (blockIdx.x == 0) {
    const int* vi = (const int*)valid_raw;
    const float* vf = (const float*)valid_raw;
    const unsigned char* vb = (const unsigned char*)valid_raw;
    for (int i = tid; i < BB * NSLOT; i += blockDim.x)
      valid_int[i] = (mode == 0) ? (vi[i] != 0)
                   : (mode == 1) ? (vf[i] != 0.0f)
                                 : (vb[i] != 0);
  }
  {
    const int* vi = (const int*)hist_raw;
    const float* vf = (const float*)hist_raw;
    const unsigned char* vb = (const unsigned char*)hist_raw;
    const int base = blockIdx.x * 1024;
    for (int i = tid; i < 1024; i += blockDim.x) {
      const int g = base + i;
      hist_int[g] = (mode == 0) ? (vi[g] != 0)
                  : (mode == 1) ? (vf[g] != 0.0f)
                                : (vb[g] != 0);
    }
  }
}

// ---------------- PK[b,n,h] = sum_k keys[b,n,k] * Wq[k,h]  (fp32) -----------
__global__ __launch_bounds__(256) void pk_kernel(const float* __restrict__ keys,
                                                 const float* __restrict__ Wq,
                                                 float* __restrict__ PK) {
  const int b = blockIdx.x >> 5;
  const int h0 = (blockIdx.x & 31) * 64;
  __shared__ float ks[64][260];
  const int tid = threadIdx.x;
  const float* kb = keys + (size_t)b * 64 * 256;
  for (int i = tid; i < 64 * 64; i += 256) {
    const int n = i >> 6, k4 = (i & 63) * 4;
    *(float4*)&ks[n][k4] = *(const float4*)&kb[n * 256 + k4];
  }
  __syncthreads();
  const int h = h0 + (tid & 63);
  const int ng = tid >> 6;
  float acc[16] = {};
  for (int k = 0; k < 256; ++k) {
    const float wq = Wq[(size_t)k * HH + h];
#pragma unroll
    for (int i = 0; i < 16; ++i) acc[i] += ks[i * 4 + ng][k] * wq;
  }
#pragma unroll
  for (int i = 0; i < 16; ++i)
    PK[((size_t)b * 64 + i * 4 + ng) * HH + h] = acc[i];
}

// -------- PK -> hi/lo bf16 MFMA-fragment layout (grid 256) ------------------
__global__ __launch_bounds__(64) void pkfrag_kernel(const float* __restrict__ PK,
                                                    unsigned short* __restrict__ PKh,
                                                    unsigned short* __restrict__ PKl) {
  const int b = blockIdx.x >> 6, kc = blockIdx.x & 63;
  const int lane = threadIdx.x, fr = lane & 15, hi4 = lane >> 4;
#pragma unroll
  for (int nt = 0; nt < 4; ++nt) {
    const float* src = &PK[((size_t)b * 64 + nt * 16 + fr) * HH + kc * 32 + hi4 * 8];
    const float4 a = *(const float4*)src;
    const float4 c = *(const float4*)(src + 4);
    B8 h, l;
    cvt8(a, c, h, l);
    const size_t off = (((size_t)(b * 64 + kc) * 4 + nt) * 64 + lane) * 8;
    *(short8*)&PKh[off] = h.v;
    *(short8*)&PKl[off] = l.v;
  }
}

// -------- VW[b][n][h] = sum_v vals[b,n,v]*Wo[h,v] -> B-frag layout bf16 -----
// VWTf elem: b*131072 + (ht*2+ks)*512 + (hi4*16+fr)*8 + j
//   where h = ht*16+fr, n = ks*32+hi4*8+j
__global__ __launch_bounds__(256) void vw_kernel(const float* __restrict__ vals,
                                                 const float* __restrict__ Wo,
                                                 unsigned short* __restrict__ VWTf) {
  const int b = blockIdx.x >> 5;
  const int h0 = (blockIdx.x & 31) * 64;
  __shared__ float vals_s[64][260];
  __shared__ float wo_s[64][261];
  const int tid = threadIdx.x;
  const float* vb = vals + (size_t)b * 64 * 256;
  for (int i = tid; i < 64 * 64; i += 256) {
    const int r = i >> 6, c4 = (i & 63) * 4;
    *(float4*)&vals_s[r][c4] = *(const float4*)&vb[r * 256 + c4];
    *(float4*)&wo_s[r][c4] = *(const float4*)&Wo[(size_t)(h0 + r) * 256 + c4];
  }
  __syncthreads();
  const int hloc = tid & 63;
  const int ng = tid >> 6;
  const int h = h0 + hloc;
  float acc[16] = {};
  for (int v = 0; v < 256; ++v) {
    const float wo = wo_s[hloc][v];
#pragma unroll
    for (int i = 0; i < 16; ++i) acc[i] += vals_s[i * 4 + ng][v] * wo;
  }
  const int ht = h >> 4, fr = h & 15;
#pragma unroll
  for (int i = 0; i < 16; ++i) {
    const int n = i * 4 + ng;
    const int ks = n >> 5, hi4 = (n >> 3) & 3, j = n & 7;
    VWTf[(size_t)b * 131072 + (size_t)(ht * 2 + ks) * 512 +
         (hi4 * 16 + fr) * 8 + j] = f2bf(acc[i]);
  }
}

// -------- attn v10: scores (split-bf16 MFMA) + softmax -> P bf16 ------------
// 16 tok/block, double-buffered LDS A, PK reg prefetch; grid 1024
__global__ __launch_bounds__(256, 4) void attn_kernel(
    const float* __restrict__ hs,
    const unsigned short* __restrict__ PKh,
    const unsigned short* __restrict__ PKl,
    const int* __restrict__ valid,
    const int* __restrict__ hist,
    unsigned short* __restrict__ PB) {   // [BT][64] bf16
  const int t0 = blockIdx.x * 16;
  const int b = blockIdx.x >> 8;         // 256 blocks per batch
  const int tid = threadIdx.x;
  const int w = tid >> 6, lane = tid & 63;
  const int fr = lane & 15, hi4 = lane >> 4;

  __shared__ __align__(16) unsigned short Ah[2][16][136], Al[2][16][136];
  __shared__ float S[16][68];

  floatx4 accA = (floatx4){0.f, 0.f, 0.f, 0.f};
  floatx4 accB = accA, accC = accA;

  const int sr = tid >> 4;        // token row 0..15
  const int sg = tid & 15;        // 8-float col group
  const float* gbase = &hs[(size_t)(t0 + sr) * HH + sg * 8];

  float4 va0 = *(const float4*)gbase;
  float4 va1 = *(const float4*)(gbase + 4);
  {
    B8 h_, l_;
    cvt8(va0, va1, h_, l_);
    *(short8*)&Ah[0][sr][sg * 8] = h_.v;
    *(short8*)&Al[0][sr][sg * 8] = l_.v;
  }
  va0 = *(const float4*)(gbase + 128);
  va1 = *(const float4*)(gbase + 132);
  short8 bhc[4], blc[4];
#pragma unroll
  for (int kcL = 0; kcL < 4; ++kcL) {
    const size_t off = ((size_t)(b * 64 + kcL) * 4 + w) * 512 + lane * 8;
    bhc[kcL] = *(const short8*)&PKh[off];
    blc[kcL] = *(const short8*)&PKl[off];
  }
  __syncthreads();

  for (int s = 0; s < 16; ++s) {
    const int buf = s & 1;
    if (s < 15) {
      B8 h_, l_;
      cvt8(va0, va1, h_, l_);
      *(short8*)&Ah[buf ^ 1][sr][sg * 8] = h_.v;
      *(short8*)&Al[buf ^ 1][sr][sg * 8] = l_.v;
    }
    if (s < 14) {
      va0 = *(const float4*)(gbase + (s + 2) * 128);
      va1 = *(const float4*)(gbase + (s + 2) * 128 + 4);
    }
    short8 bhn[4], bln[4];
    if (s < 15) {
#pragma unroll
      for (int kcL = 0; kcL < 4; ++kcL) {
        const size_t off = ((size_t)(b * 64 + (s + 1) * 4 + kcL) * 4 + w) * 512 + lane * 8;
        bhn[kcL] = *(const short8*)&PKh[off];
        bln[kcL] = *(const short8*)&PKl[off];
      }
    }
#pragma unroll
    for (int kcL = 0; kcL < 4; ++kcL) {
      const short8 ah = *(const short8*)&Ah[buf][fr][kcL * 32 + hi4 * 8];
      const short8 al = *(const short8*)&Al[buf][fr][kcL * 32 + hi4 * 8];
      accA = __builtin_amdgcn_mfma_f32_16x16x32_bf16(ah, bhc[kcL], accA, 0, 0, 0);
      accB = __builtin_amdgcn_mfma_f32_16x16x32_bf16(al, bhc[kcL], accB, 0, 0, 0);
      accC = __builtin_amdgcn_mfma_f32_16x16x32_bf16(ah, blc[kcL], accC, 0, 0, 0);
    }
    __syncthreads();
    if (s < 15) {
#pragma unroll
      for (int kcL = 0; kcL < 4; ++kcL) { bhc[kcL] = bhn[kcL]; blc[kcL] = bln[kcL]; }
    }
  }

  const floatx4 acc = accA + accB + accC;
#pragma unroll
  for (int rr = 0; rr < 4; ++rr)
    S[hi4 * 4 + rr][w * 16 + fr] = acc[rr];
  __syncthreads();

  // softmax + masks -> P (wave w handles tokens w*4..w*4+3; lane = slot)
  const int vmy = valid[b * 64 + lane];
  const unsigned long long bal = __ballot(vmy != 0);
  const float any = (bal != 0ull) ? 1.0f : 0.0f;
#pragma unroll
  for (int i = 0; i < 4; ++i) {
    const int tt = w * 4 + i;
    const int tok = t0 + tt;
    float s = vmy ? S[tt][lane] : NEGV;
    float m = s;
#pragma unroll
    for (int o = 32; o; o >>= 1) m = fmaxf(m, __shfl_xor(m, o));
    const float e = __expf(s - m);
    float sum = e;
#pragma unroll
    for (int o = 32; o; o >>= 1) sum += __shfl_xor(sum, o);
    const float allowed = hist[tok] ? 0.0f : 1.0f;
    PB[(size_t)tok * 64 + lane] = f2bf(e / sum * any * allowed);
  }
}

// -------- fused output via MFMA: out = LN(hs + P·VW^T) ----------------------
// block: 16 tokens x 2048 cols, 512 thr (8 waves, 256-col strip each).
// grid 1024. A-frags direct from PB; B-frags from VWTf (4-deep ring prefetch).
__global__ __launch_bounds__(512) void fuse_mfma_kernel(
    const unsigned short* __restrict__ PB,    // [BT][64] bf16
    const unsigned short* __restrict__ VWTf,  // frag layout
    const float* __restrict__ RES,            // hs
    const float* __restrict__ gamma,
    const float* __restrict__ beta,
    float* __restrict__ out) {
  const int tok0 = blockIdx.x * 16;
  const int b = tok0 >> 12;
  const int tid = threadIdx.x;
  const int w = tid >> 6, lane = tid & 63;
  const int fr = lane & 15, hi4 = lane >> 4;

  __shared__ float part[16][8][2];
  __shared__ float stats[16][2];

  // A-frags: lane holds P[tok0+fr][ks*32 + hi4*8 .. +8]
  const short8 af0 = *(const short8*)&PB[(size_t)(tok0 + fr) * 64 + hi4 * 8];
  const short8 af1 = *(const short8*)&PB[(size_t)(tok0 + fr) * 64 + 32 + hi4 * 8];

  floatx4 acc[16];
#pragma unroll
  for (int j = 0; j < 16; ++j) acc[j] = (floatx4){0.f, 0.f, 0.f, 0.f};

  // wave's B strip: global tile ht = w*16 + ht16
  const unsigned short* vbase =
      &VWTf[(size_t)b * 131072 + (size_t)(w * 16) * 2 * 512 + lane * 8];

  short8 br0[4], br1[4];
#pragma unroll
  for (int p = 0; p < 4; ++p) {
    br0[p] = *(const short8*)&vbase[(size_t)(p * 2 + 0) * 512];
    br1[p] = *(const short8*)&vbase[(size_t)(p * 2 + 1) * 512];
  }
#pragma unroll
  for (int ht = 0; ht < 16; ++ht) {
    const int cc = ht & 3;   // static after unroll
    acc[ht] = __builtin_amdgcn_mfma_f32_16x16x32_bf16(af0, br0[cc], acc[ht], 0, 0, 0);
    acc[ht] = __builtin_amdgcn_mfma_f32_16x16x32_bf16(af1, br1[cc], acc[ht], 0, 0, 0);
    if (ht < 12) {
      br0[cc] = *(const short8*)&vbase[(size_t)((ht + 4) * 2 + 0) * 512];
      br1[cc] = *(const short8*)&vbase[(size_t)((ht + 4) * 2 + 1) * 512];
    }
  }

  // residual + per-row partial stats (row = hi4*4+rr, col = w*256+ht*16+fr)
  float s4[4] = {}, q4[4] = {};
#pragma unroll
  for (int ht = 0; ht < 16; ++ht) {
    const int col = w * 256 + ht * 16 + fr;
#pragma unroll
    for (int rr = 0; rr < 4; ++rr) {
      const int row = tok0 + hi4 * 4 + rr;
      const float x = acc[ht][rr] + RES[(size_t)row * HH + col];
      acc[ht][rr] = x;
      s4[rr] += x;
      q4[rr] += x * x;
    }
  }
#pragma unroll
  for (int rr = 0; rr < 4; ++rr) {
#pragma unroll
    for (int o = 1; o < 16; o <<= 1) {   // reduce over fr within 16-lane group
      s4[rr] += __shfl_xor(s4[rr], o);
      q4[rr] += __shfl_xor(q4[rr], o);
    }
  }
  if (fr == 0) {
#pragma unroll
    for (int rr = 0; rr < 4; ++rr) {
      part[hi4 * 4 + rr][w][0] = s4[rr];
      part[hi4 * 4 + rr][w][1] = q4[rr];
    }
  }
  __syncthreads();
  if (tid < 16) {
    float S = 0.f, Q = 0.f;
#pragma unroll
    for (int ww = 0; ww < 8; ++ww) {
      S += part[tid][ww][0];
      Q += part[tid][ww][1];
    }
    const float mu = S * (1.0f / HH);
    const float var = Q * (1.0f / HH) - mu * mu;
    stats[tid][0] = mu;
    stats[tid][1] = rsqrtf(var + EPSV);
  }
  __syncthreads();

  // normalize + store
#pragma unroll
  for (int ht = 0; ht < 16; ++ht) {
    const int col = w * 256 + ht * 16 + fr;
    const float g = gamma[col], bb = beta[col];
#pragma unroll
    for (int rr = 0; rr < 4; ++rr) {
      const int row = hi4 * 4 + rr;
      out[(size_t)(tok0 + row) * HH + col] =
          (acc[ht][rr] - stats[row][0]) * stats[row][1] * g + bb;
    }
  }
}

extern "C" void kernel_launch(void* const* d_in, const int* in_sizes, int n_in,
                              void* d_out, int out_size, void* d_ws, size_t ws_size,
                              hipStream_t stream) {
  const float* hs    = (const float*)d_in[0];
  const float* keys  = (const float*)d_in[1];
  const float* vals  = (const float*)d_in[2];
  const float* Wq    = (const float*)d_in[3];
  const float* Wo    = (const float*)d_in[4];
  const float* gamma = (const float*)d_in[5];
  const float* beta  = (const float*)d_in[6];
  const void* valid_raw = d_in[7];
  const void* hist_raw  = d_in[8];
  float* out = (float*)d_out;

  char* w = (char*)d_ws;
  float* PK            = (float*)w;                           // 2 MB
  unsigned short* PKh  = (unsigned short*)(w + (2u << 20));   // 1 MB
  unsigned short* PKl  = (unsigned short*)(w + (3u << 20));   // 1 MB
  unsigned short* VWTf = (unsigned short*)(w + (4u << 20));   // 1 MB
  unsigned short* PB   = (unsigned short*)(w + (5u << 20));   // 2 MB
  int* valid_int = (int*)(w + (7u << 20));
  int* hist_int  = valid_int + BB * NSLOT;

  mask_convert_kernel<<<dim3(16), dim3(256), 0, stream>>>(valid_raw, hist_raw,
                                                          valid_int, hist_int);
  pk_kernel<<<dim3(128), dim3(256), 0, stream>>>(keys, Wq, PK);
  pkfrag_kernel<<<dim3(256), dim3(64), 0, stream>>>(PK, PKh, PKl);
  vw_kernel<<<dim3(128), dim3(256), 0, stream>>>(vals, Wo, VWTf);
  attn_kernel<<<dim3(BT / 16), dim3(256), 0, stream>>>(
      hs, PKh, PKl, valid_int, hist_int, PB);
  fuse_mfma_kernel<<<dim3(BT / 16), dim3(512), 0, stream>>>(
      PB, VWTf, hs, gamma, beta, out);
}